// Round 7
// baseline (243.961 us; speedup 1.0000x reference)
//
#include <hip/hip_runtime.h>

#define D 256
#define VOCAB 4096
#define NTOT 16384      // 16 * 32 * 32
#define N_OUT0 4194304  // 16*256*32*32
#define MARGIN 0.95f

typedef _Float16 half8 __attribute__((ext_vector_type(8)));
typedef float f32x4 __attribute__((ext_vector_type(4)));

__device__ __forceinline__ void gld16(const void* g, void* l) {
    __builtin_amdgcn_global_load_lds(
        (const __attribute__((address_space(1))) void*)g,
        (__attribute__((address_space(3))) void*)l, 16, 0, 0);
}

__device__ __forceinline__ unsigned long long pack_key(float d, int v) {
    unsigned u = __float_as_uint(d);
    u ^= ((unsigned)((int)u >> 31)) | 0x80000000u;  // monotonic float->uint
    return ((unsigned long long)u << 32) | (unsigned)v;
}

// ---------------- pack ----------------
// Apk halfs: [bm 64][w 4][kk 2][q 4][r 256][j 8]   (k = w*64+kk*32+q*8+j, row = bm*256+r)
// Bpk halfs: [bn 32][w 4][kk 2][q 4][r 128][j 8]   with PERMUTED rows:
//   packed row r holds emb row v0 + (r&64) + (r&15)*4 + ((r&63)>>4)
//   so MFMA lane j16, slot nt covers v = n0 + wn*64 + j16*4 + nt (4 consecutive per lane)
__global__ __launch_bounds__(256) void k_pack(const float* __restrict__ h,
                                              const float* __restrict__ emb,
                                              _Float16* __restrict__ Apk,
                                              _Float16* __restrict__ Bpk,
                                              float* __restrict__ esq) {
    __shared__ float S[16384];
    const int tid = threadIdx.x;
    const int bid = blockIdx.x;
    if (bid < 256) {
        const int bm = bid >> 2, w = bid & 3;
        const int b = bm >> 2, p0 = (bm & 3) << 8;
#pragma unroll 4
        for (int cl = 0; cl < 64; ++cl)
            S[cl * 256 + tid] =
                h[((size_t)b << 18) + ((size_t)(w * 64 + cl) << 10) + (size_t)(p0 + tid)];
        __syncthreads();
        _Float16* dstA = Apk + (size_t)bm * 65536 + (size_t)w * 16384;
#pragma unroll
        for (int kk = 0; kk < 2; ++kk)
#pragma unroll
            for (int q = 0; q < 4; ++q) {
                alignas(16) _Float16 hv[8];
#pragma unroll
                for (int j = 0; j < 8; ++j) hv[j] = (_Float16)S[(kk * 32 + q * 8 + j) * 256 + tid];
                *(half8*)(dstA + (kk * 4 + q) * 2048 + tid * 8) = *(half8*)hv;
            }
    } else {
        const int bn = bid - 256, v0 = bn << 7;
        float eacc = 0.f;
        _Float16* dstB = Bpk + (size_t)bn * 32768;
        const int kk = tid >> 7, r = tid & 127;
        const int sr = (r & 64) + ((r & 15) * 4) + ((r & 63) >> 4);
        for (int w = 0; w < 4; ++w) {
            __syncthreads();
#pragma unroll 4
            for (int i = 0; i < 32; ++i) {
                int rr = i * 4 + (tid >> 6), cc = tid & 63;
                S[rr * 65 + cc] = emb[(size_t)(v0 + rr) * 256 + w * 64 + cc];
            }
            __syncthreads();
            if (tid < 128)
#pragma unroll 4
                for (int cc = 0; cc < 64; ++cc) { float x = S[tid * 65 + cc]; eacc = fmaf(x, x, eacc); }
#pragma unroll
            for (int q = 0; q < 4; ++q) {
                alignas(16) _Float16 ev[8];
#pragma unroll
                for (int j = 0; j < 8; ++j) ev[j] = (_Float16)S[sr * 65 + kk * 32 + q * 8 + j];
                *(half8*)(dstB + w * 8192 + (kk * 4 + q) * 1024 + r * 8) = *(half8*)ev;
            }
        }
        if (tid < 128) esq[v0 + tid] = eacc;
    }
}

// ---------------- hi-fp16 distance GEMM + per-(row, 32-group) float min ----------------
__global__ __launch_bounds__(256, 2) void k_gemm(const _Float16* __restrict__ Apk,
                                                 const _Float16* __restrict__ Bpk,
                                                 const float* __restrict__ esq,
                                                 float* __restrict__ top1) {
    __shared__ _Float16 As[16384];  // 32 KB
    __shared__ _Float16 Bs[8192];   // 16 KB

    const int tid = threadIdx.x;
    const int bn = blockIdx.x >> 6, bm = blockIdx.x & 63;
    const int m0 = bm << 8, n0 = bn << 7;
    const int wv = tid >> 6, l = tid & 63;
    const int wm = wv & 1, wn = wv >> 1;
    const int quad = l >> 4, j16 = l & 15;

    f32x4 acc[8][4];
#pragma unroll
    for (int i = 0; i < 8; ++i)
#pragma unroll
        for (int j = 0; j < 4; ++j) acc[i][j] = (f32x4)0.0f;

    const char* Ag = (const char*)(Apk + (size_t)bm * 65536) + tid * 16;
    const char* Bg = (const char*)(Bpk + (size_t)bn * 32768) + tid * 16;
    _Float16* Asw = As + tid * 8;
    _Float16* Bsw = Bs + tid * 8;
    const _Float16* aB = As + quad * 2048 + (wm * 128 + j16) * 8;
    const _Float16* bB = Bs + quad * 1024 + (wn * 64 + j16) * 8;

    for (int w = 0; w < 4; ++w) {
#pragma unroll
        for (int i = 0; i < 8; ++i) gld16(Ag + w * 32768 + i * 4096, Asw + i * 2048);
#pragma unroll
        for (int i = 0; i < 4; ++i) gld16(Bg + w * 16384 + i * 4096, Bsw + i * 2048);
        __syncthreads();
#pragma unroll
        for (int kk = 0; kk < 2; ++kk) {
            half8 af[8], bf[4];
#pragma unroll
            for (int mt = 0; mt < 8; ++mt) af[mt] = *(const half8*)(aB + kk * 8192 + mt * 128);
#pragma unroll
            for (int nt = 0; nt < 4; ++nt) bf[nt] = *(const half8*)(bB + kk * 4096 + nt * 128);
#pragma unroll
            for (int mt = 0; mt < 8; ++mt)
#pragma unroll
                for (int nt = 0; nt < 4; ++nt)
                    acc[mt][nt] = __builtin_amdgcn_mfma_f32_16x16x32_f16(af[mt], bf[nt], acc[mt][nt], 0, 0, 0);
        }
        __syncthreads();
    }

    const float4 es4 = *(const float4*)(esq + n0 + wn * 64 + j16 * 4);
    const size_t tbase = ((size_t)m0 + wm * 128) * 128 + (unsigned)(bn * 4 + wn * 2 + (j16 >> 3));
#pragma unroll
    for (int mt = 0; mt < 8; ++mt) {
#pragma unroll
        for (int r = 0; r < 4; ++r) {
            float d0 = es4.x - 2.0f * acc[mt][0][r];
            float d1 = es4.y - 2.0f * acc[mt][1][r];
            float d2 = es4.z - 2.0f * acc[mt][2][r];
            float d3 = es4.w - 2.0f * acc[mt][3][r];
            float mn = fminf(fminf(d0, d1), fminf(d2, d3));
            mn = fminf(mn, __shfl_xor(mn, 1, 64));
            mn = fminf(mn, __shfl_xor(mn, 2, 64));
            mn = fminf(mn, __shfl_xor(mn, 4, 64));
            if ((j16 & 7) == 0)
                top1[tbase + (size_t)(mt * 16 + quad * 4 + r) * 128] = mn;
        }
    }
}

// ---------------- fused refine + gather: 512 blocks x 32 rows ----------------
// Phase 1: stage h tile coalesced into LDS.
// Phase 2: wave-per-row refine (verify passing 32-code groups in exact fp32, h from LDS).
// Phase 3: gather z_q, write out0/out1, loss partial.
__global__ __launch_bounds__(256) void k_finish(const float* __restrict__ h,
                                                const float* __restrict__ emb,
                                                const float* __restrict__ esq,
                                                const float* __restrict__ top1,
                                                float* __restrict__ out0,
                                                float* __restrict__ out1,
                                                float* __restrict__ plsum) {
    __shared__ float Sh[32][257];
    __shared__ float zq[32][260];
    __shared__ int idxs[32];
    __shared__ float wred[4];

    const int tid = threadIdx.x;
    const int lane = tid & 63;
    const int w = tid >> 6;
    const int n0 = blockIdx.x * 32;
    const int b = n0 >> 10;
    const int p0 = n0 & 1023;
    const size_t base = (size_t)b << 18;

    // phase 1: stage h (coalesced: 32 consecutive p per c-row)
    {
        const int pp = tid & 31, c0 = tid >> 5;
#pragma unroll 4
        for (int it = 0; it < 32; ++it) {
            int c = it * 8 + c0;
            Sh[pp][c] = h[base + ((size_t)c << 10) + (size_t)(p0 + pp)];
        }
    }
    __syncthreads();

    // phase 2: refine rows w*8 .. w*8+7
#pragma unroll 1
    for (int rr = 0; rr < 8; ++rr) {
        const int r = w * 8 + rr;
        const int n = n0 + r;
        const float2 gm = *(const float2*)(top1 + ((size_t)n << 7) + lane * 2);
        float m1 = fminf(gm.x, gm.y);
#pragma unroll
        for (int m = 32; m >= 1; m >>= 1) m1 = fminf(m1, __shfl_xor(m1, m, 64));
        const float thr = m1 + MARGIN;

        const float h0 = Sh[r][lane * 4 + 0];
        const float h1 = Sh[r][lane * 4 + 1];
        const float h2 = Sh[r][lane * 4 + 2];
        const float h3 = Sh[r][lane * 4 + 3];

        unsigned long long best = ~0ULL;
#pragma unroll
        for (int j = 0; j < 2; ++j) {
            unsigned long long mask = __ballot((j == 0 ? gm.x : gm.y) <= thr);
            while (mask) {
                const int s = __builtin_ctzll(mask);
                mask &= mask - 1;
                const int vg = (s * 2 + j) << 5;  // base code of 32-group
                for (int t = 0; t < 32; ++t) {
                    const int v = vg + t;
                    float4 e4 = *(const float4*)(emb + ((size_t)v << 8) + lane * 4);
                    float part = h0 * e4.x;
                    part = fmaf(h1, e4.y, part);
                    part = fmaf(h2, e4.z, part);
                    part = fmaf(h3, e4.w, part);
#pragma unroll
                    for (int m = 32; m >= 1; m >>= 1) part += __shfl_xor(part, m, 64);
                    unsigned long long ke = pack_key(esq[v] - 2.0f * part, v);
                    best = ke < best ? ke : best;
                }
            }
        }
        if (lane == 0) {
            const int idx = (int)(best & 0xFFFFFFFFULL);
            idxs[r] = idx;
            out1[n] = (float)idx;
        }
    }
    __syncthreads();

    // phase 3: gather z_q rows, write out0, loss partial
#pragma unroll
    for (int rr = 0; rr < 8; ++rr) {
        int r = w * 8 + rr;
        float4 e4 = *(const float4*)(emb + ((size_t)idxs[r] << 8) + lane * 4);
        *(float4*)&zq[r][lane * 4] = e4;
    }
    __syncthreads();

    float lsum = 0.0f;
#pragma unroll 4
    for (int it = 0; it < 32; ++it) {
        int c = it * 8 + (tid >> 5);
        int pp = tid & 31;
        float z = zq[pp][c];
        float hv = Sh[pp][c];
        out0[base + ((size_t)c << 10) + (size_t)(p0 + pp)] = hv + (z - hv);
        float d = hv - z;
        lsum = fmaf(d, d, lsum);
    }
#pragma unroll
    for (int m = 32; m >= 1; m >>= 1) lsum += __shfl_xor(lsum, m, 64);
    if (lane == 0) wred[w] = lsum;
    __syncthreads();
    if (tid == 0) plsum[blockIdx.x] = wred[0] + wred[1] + wred[2] + wred[3];
}

// ---------------- final loss reduce ----------------
__global__ __launch_bounds__(256) void k_fin(const float* __restrict__ plsum,
                                             float* __restrict__ out2) {
    __shared__ float wred[4];
    const int tid = threadIdx.x;
    float s = plsum[tid] + plsum[tid + 256];
#pragma unroll
    for (int m = 32; m >= 1; m >>= 1) s += __shfl_xor(s, m, 64);
    if ((tid & 63) == 0) wred[tid >> 6] = s;
    __syncthreads();
    if (tid == 0) out2[0] = (wred[0] + wred[1] + wred[2] + wred[3]) * (1.0f / (float)N_OUT0);
}

extern "C" void kernel_launch(void* const* d_in, const int* in_sizes, int n_in,
                              void* d_out, int out_size, void* d_ws, size_t ws_size,
                              hipStream_t stream) {
    const float* h = (const float*)d_in[0];
    const float* emb = (const float*)d_in[1];
    float* out0 = (float*)d_out;
    float* out1 = out0 + N_OUT0;
    float* out2 = out1 + NTOT;

    // ws layout (bytes), total ~18.9 MB < 21.1 MB available:
    char* w = (char*)d_ws;
    _Float16* Apk = (_Float16*)(w);                //  8 MB
    _Float16* Bpk = (_Float16*)(w + 8388608);      //  2 MB
    float* top1 = (float*)(w + 10485760);          //  8 MB (16384 x 128)
    float* esq = (float*)(w + 18874368);           // 16 KB
    float* plsum = (float*)(w + 18890752);         //  2 KB

    hipLaunchKernelGGL(k_pack, dim3(288), dim3(256), 0, stream, h, emb, Apk, Bpk, esq);
    hipLaunchKernelGGL(k_gemm, dim3(2048), dim3(256), 0, stream, Apk, Bpk, esq, top1);
    hipLaunchKernelGGL(k_finish, dim3(NTOT / 32), dim3(256), 0, stream, h, emb, esq, top1, out0, out1, plsum);
    hipLaunchKernelGGL(k_fin, dim3(1), dim3(256), 0, stream, plsum, out2);
}